// Round 7
// baseline (425.528 us; speedup 1.0000x reference)
//
#include <hip/hip_runtime.h>
#include <hip/hip_bf16.h>

// GPT2 block fwd: B=2,S=2048,D=1024,H=16,DH=64,F=4096. fp32 in/out, bf16 MFMA.
// ws layout (bytes):
//   [0,24M)   qkv bf16 [4096][3072]  (V cols unused; slot reused by ffn 32MB)
//   [24M,32M) vt bf16 [32 bh][64 d][2048 s]  (written by QKV GEMM epilogue)
//   [32M,40M) hbuf bf16: h (LN1 out), later attention output o
//   [40M,56M) add1 fp32 [4096][1024]
//   [56M,64M) h2 bf16
//   [64M,70M) qkvT bf16 | [70M,72M) woT | [72M,80M) w1T | [80M,88M) w2T
//   [88M,..)  bias_qkv fp32 [3072]
// total ~88MB.

#define BDIM 1024
#define SEQ 2048
#define NH 16
#define DHEAD 64
#define FDIM 4096
#define QKVD 3072

typedef __attribute__((ext_vector_type(8))) short short8v;
typedef __attribute__((ext_vector_type(4))) float floatx4;

__device__ __forceinline__ unsigned short f2bf(float f) {
    unsigned int u = __float_as_uint(f);
    unsigned int r = u + 0x7FFFu + ((u >> 16) & 1u);
    return (unsigned short)(r >> 16);
}
__device__ __forceinline__ unsigned int pack2bf(float a, float b) {
    return (unsigned int)f2bf(a) | ((unsigned int)f2bf(b) << 16);
}

__device__ __forceinline__ void load16_lds(const unsigned short* g, short* l) {
    __builtin_amdgcn_global_load_lds((const __attribute__((address_space(1))) void*)g,
                                     (__attribute__((address_space(3))) void*)l, 16, 0, 0);
}

template <int N>
__device__ __forceinline__ void wait_vmcnt() {
    asm volatile("s_waitcnt vmcnt(%0)" ::"n"(N) : "memory");
}

// ---------------- batched weight fp32 [K,N] -> bf16 [N,K] transpose ----------
__global__ __launch_bounds__(256) void transpose_all(const float* __restrict__ wq,
                                                     const float* __restrict__ wk,
                                                     const float* __restrict__ wv,
                                                     const float* __restrict__ wo,
                                                     const float* __restrict__ w1,
                                                     const float* __restrict__ w2,
                                                     unsigned short* __restrict__ qkvT,
                                                     unsigned short* __restrict__ woT,
                                                     unsigned short* __restrict__ w1T,
                                                     unsigned short* __restrict__ w2T) {
    const int g = blockIdx.x;
    const float* W;
    unsigned short* Wt;
    int K, N, tx, ty;
    if (g < 4096) {
        const int w = g >> 10, tile = g & 1023;
        tx = tile & 31; ty = tile >> 5; K = 1024; N = 1024;
        W = (w == 0) ? wq : (w == 1) ? wk : (w == 2) ? wv : wo;
        Wt = (w == 3) ? woT : qkvT + (size_t)w * 1024 * 1024;
    } else if (g < 8192) {
        const int tile = g - 4096;
        tx = tile & 127; ty = tile >> 7; K = 1024; N = 4096;
        W = w1; Wt = w1T;
    } else {
        const int tile = g - 8192;
        tx = tile & 31; ty = tile >> 5; K = 4096; N = 1024;
        W = w2; Wt = w2T;
    }
    __shared__ float tile[32][33];
    const int t = threadIdx.x;
    const int r = t >> 3, c4 = (t & 7) * 4;
    const int n0 = tx * 32, k0 = ty * 32;
    float4 p = *(const float4*)(W + (size_t)(k0 + r) * N + n0 + c4);
    tile[r][c4 + 0] = p.x;
    tile[r][c4 + 1] = p.y;
    tile[r][c4 + 2] = p.z;
    tile[r][c4 + 3] = p.w;
    __syncthreads();
    ushort4 ou;
    ou.x = f2bf(tile[c4 + 0][r]);
    ou.y = f2bf(tile[c4 + 1][r]);
    ou.z = f2bf(tile[c4 + 2][r]);
    ou.w = f2bf(tile[c4 + 3][r]);
    *(ushort4*)(Wt + (size_t)(n0 + r) * K + k0 + c4) = ou;
}

__global__ void concat_bias(const float* __restrict__ a, const float* __restrict__ b,
                            const float* __restrict__ c, float* __restrict__ out) {
    int i = blockIdx.x * 256 + threadIdx.x;
    out[i] = (i < 1024) ? a[i] : (i < 2048 ? b[i - 1024] : c[i - 2048]);
}

// ---------------- LayerNorm: fp32 in -> bf16 out ----------------
__global__ __launch_bounds__(256) void ln_kernel(const float* __restrict__ x,
                                                 const float* __restrict__ g,
                                                 const float* __restrict__ bb,
                                                 unsigned short* __restrict__ out) {
    const int row = blockIdx.x;
    const int t = threadIdx.x;
    const int c = t * 4;
    float4 p = *(const float4*)(x + (size_t)row * BDIM + c);
    float s = p.x + p.y + p.z + p.w;
    float sq = p.x * p.x + p.y * p.y + p.z * p.z + p.w * p.w;
    for (int off = 1; off < 64; off <<= 1) {
        s += __shfl_xor(s, off);
        sq += __shfl_xor(sq, off);
    }
    __shared__ float ssum[4], ssq[4];
    const int wave = t >> 6, lane = t & 63;
    if (lane == 0) { ssum[wave] = s; ssq[wave] = sq; }
    __syncthreads();
    s = ssum[0] + ssum[1] + ssum[2] + ssum[3];
    sq = ssq[0] + ssq[1] + ssq[2] + ssq[3];
    const float mean = s * (1.0f / BDIM);
    const float var = sq * (1.0f / BDIM) - mean * mean;
    const float rstd = rsqrtf(var + 1e-5f);
    float4 gg = *(const float4*)(g + c);
    float4 bv = *(const float4*)(bb + c);
    ushort4 o;
    o.x = f2bf((p.x - mean) * rstd * gg.x + bv.x);
    o.y = f2bf((p.y - mean) * rstd * gg.y + bv.y);
    o.z = f2bf((p.z - mean) * rstd * gg.z + bv.z);
    o.w = f2bf((p.w - mean) * rstd * gg.w + bv.w);
    *(ushort4*)(out + (size_t)row * BDIM + c) = o;
}

// ------- 8-wave deep-pipelined GEMM (T2+T3+T4+T5): 256x256 tile, BK=32 -------
// 512 threads = 8 waves (2M x 4N), wave-tile 128x64, acc[8][4].
// LDS: 4-slot ring of K-tiles (slot = A[256][32] + B[256][32] = 32KB) = 128KB.
// Schedule: 3-tile staging lookahead; per iter: vmcnt(8) (2 tiles stay in
// flight, never drains to 0) + 1 barrier; 2 phases of {2 gload_lds || 12
// ds_read_b128 || 16 MFMA} with setprio(1) around each MFMA cluster.
// Slot safety: iter j stages tile j+3 into slot (j-1)&3; all waves finished
// reading that slot in iter j-1 (ds_reads forced complete by lgkmcnt before
// their MFMAs, which precede the iter-j barrier).
// Swizzle (T2): 16B chunk index XOR row&3, applied to the GLOBAL source addr
// (gload_lds writes LDS linearly) and to the ds_read addr (involution).
// Reads go from 8-way to ~4-way quarter-wave conflicts.
template <int GELU>
__global__ __launch_bounds__(512, 2) void mfma_gemm8(
        const unsigned short* __restrict__ A,   // [M][K] bf16
        const unsigned short* __restrict__ Bt,  // [N][K] bf16
        const float* __restrict__ bias,
        unsigned short* __restrict__ C,         // [M][N] bf16
        int M, int N, int K) {
    __shared__ __align__(16) unsigned short lds[4][16384];  // A @0, B @8192 (shorts)
    const int t = threadIdx.x;
    const int lane = t & 63, wave = t >> 6;
    const int mlane = lane & 15, quad = lane >> 4;
    const int wm = wave >> 2, wn = wave & 3;

    // XCD swizzle (grid 256 = 32/XCD, bijective)
    const int nwg = gridDim.x * gridDim.y;
    int bid = blockIdx.y * gridDim.x + blockIdx.x;
    bid = (bid & 7) * (nwg >> 3) + (bid >> 3);
    const int bx = bid % gridDim.x, by = bid / gridDim.x;
    const int m0 = by * 256, n0 = bx * 256;

    // staging: thread t covers 16B-chunks t and 512+t of each region.
    // LDS chunk L: row = L>>2, c = L&3; source chunk = c ^ (row&3).
    const int srow = t >> 2;
    const int schunk = (t & 3) ^ (srow & 3);
    const unsigned short* ga0 = A + (size_t)(m0 + srow) * K + schunk * 8;
    const unsigned short* ga1 = A + (size_t)(m0 + 128 + srow) * K + schunk * 8;
    const unsigned short* gb0 = Bt + (size_t)(n0 + srow) * K + schunk * 8;
    const unsigned short* gb1 = Bt + (size_t)(n0 + 128 + srow) * K + schunk * 8;

    auto stageA = [&](int s, int k0) {
        load16_lds(ga0 + k0, (short*)&lds[s][t * 8]);
        load16_lds(ga1 + k0, (short*)&lds[s][4096 + t * 8]);
    };
    auto stageB = [&](int s, int k0) {
        load16_lds(gb0 + k0, (short*)&lds[s][8192 + t * 8]);
        load16_lds(gb1 + k0, (short*)&lds[s][12288 + t * 8]);
    };

    floatx4 acc[8][4];
#pragma unroll
    for (int mi = 0; mi < 8; ++mi)
#pragma unroll
        for (int ni = 0; ni < 4; ++ni) {
            floatx4 z = {0.0f, 0.0f, 0.0f, 0.0f};
            acc[mi][ni] = z;
        }

    // prologue: tiles 0,1,2 -> slots 0,1,2 (12 loads in flight)
    stageA(0, 0);  stageB(0, 0);
    stageA(1, 32); stageB(1, 32);
    stageA(2, 64); stageB(2, 64);

    const int aoff = (wm * 128 + mlane) * 32;         // + mi*512 shorts
    const int boff = 8192 + (wn * 64 + mlane) * 32;   // + ni*512 shorts
    const int coff = (quad ^ (mlane & 3)) * 8;        // swizzled 16B chunk

    const int nt = K >> 5;  // 32

    auto body = [&](int j, bool dostage) {
        const int s = j & 3;
        const unsigned short* sl = &lds[s][0];
        if (dostage) stageA((j + 3) & 3, (j + 3) << 5);
        short8v b[4], a[4];
#pragma unroll
        for (int ni = 0; ni < 4; ++ni)
            b[ni] = *(const short8v*)&sl[boff + ni * 512 + coff];
#pragma unroll
        for (int mi = 0; mi < 4; ++mi)
            a[mi] = *(const short8v*)&sl[aoff + mi * 512 + coff];
        __builtin_amdgcn_s_setprio(1);
#pragma unroll
        for (int mi = 0; mi < 4; ++mi)
#pragma unroll
            for (int ni = 0; ni < 4; ++ni)
                acc[mi][ni] = __builtin_amdgcn_mfma_f32_16x16x32_bf16(b[ni], a[mi], acc[mi][ni], 0, 0, 0);
        __builtin_amdgcn_s_setprio(0);
        if (dostage) stageB((j + 3) & 3, (j + 3) << 5);
#pragma unroll
        for (int mi = 0; mi < 4; ++mi)
            a[mi] = *(const short8v*)&sl[aoff + (mi + 4) * 512 + coff];
        __builtin_amdgcn_s_setprio(1);
#pragma unroll
        for (int mi = 0; mi < 4; ++mi)
#pragma unroll
            for (int ni = 0; ni < 4; ++ni)
                acc[mi + 4][ni] = __builtin_amdgcn_mfma_f32_16x16x32_bf16(b[ni], a[mi], acc[mi + 4][ni], 0, 0, 0);
        __builtin_amdgcn_s_setprio(0);
    };

    for (int j = 0; j < nt - 2; ++j) {
        wait_vmcnt<8>();                  // tile j fully landed (own loads; all
        __builtin_amdgcn_s_barrier();     // waves' via barrier)
        asm volatile("" ::: "memory");
        __builtin_amdgcn_sched_barrier(0);
        body(j, j + 3 < nt);
    }
    wait_vmcnt<4>();
    __builtin_amdgcn_s_barrier();
    asm volatile("" ::: "memory");
    __builtin_amdgcn_sched_barrier(0);
    body(nt - 2, false);
    wait_vmcnt<0>();
    __builtin_amdgcn_s_barrier();
    asm volatile("" ::: "memory");
    __builtin_amdgcn_sched_barrier(0);
    body(nt - 1, false);

    // epilogue: thread holds row = m0+wm*128+mi*16+mlane, 4 consecutive cols
#pragma unroll
    for (int mi = 0; mi < 8; ++mi) {
        const int row = m0 + wm * 128 + mi * 16 + mlane;
        unsigned short* crow = C + (size_t)row * N;
#pragma unroll
        for (int ni = 0; ni < 4; ++ni) {
            const int col0 = n0 + wn * 64 + ni * 16 + quad * 4;
            const float4 bv4 = *(const float4*)(bias + col0);
            float v0 = acc[mi][ni][0] + bv4.x;
            float v1 = acc[mi][ni][1] + bv4.y;
            float v2 = acc[mi][ni][2] + bv4.z;
            float v3 = acc[mi][ni][3] + bv4.w;
            if (GELU) {
                v0 = 0.5f * v0 * (1.0f + erff(v0 * 0.70710678118654752f));
                v1 = 0.5f * v1 * (1.0f + erff(v1 * 0.70710678118654752f));
                v2 = 0.5f * v2 * (1.0f + erff(v2 * 0.70710678118654752f));
                v3 = 0.5f * v3 * (1.0f + erff(v3 * 0.70710678118654752f));
            }
            uint2 pk;
            pk.x = pack2bf(v0, v1);
            pk.y = pack2bf(v2, v3);
            *(uint2*)(crow + col0) = pk;
        }
    }
}

// ---------------- MFMA GEMM, BK=64 (two BK=32 sub-tiles per barrier) ----------
// 2-phase loop (stage both K-halves -> sync -> compute) — QKV/wo/w2.
template <int BM, int BN, int RES, int GELU, int OBF16, int QSCALE = 0, int VOUT = 0, int SWAP = 1>
__global__ __launch_bounds__(256, (BN == 256) ? 2 : ((BM == 64) ? 4 : 3)) void mfma_gemm(
        const unsigned short* __restrict__ A,
        const unsigned short* __restrict__ Bt,
        const float* __restrict__ bias,
        const float* __restrict__ res,
        void* __restrict__ Cv,
        unsigned short* __restrict__ vtout,
        int M, int N, int K) {
    constexpr int NI = (BN == 256) ? 8 : 4;
    constexpr int MI = (BN >= 128) ? 4 : (BM == 128 ? 2 : 1);
    constexpr int CHA = BM * 4;  // 16B-chunks per A k-half
    constexpr int CHB = BN * 4;  // 16B-chunks per B k-half
    __shared__ short As[2][BM * 32];
    __shared__ short Bs[2][BN * 32];
    const int t = threadIdx.x;
    const int wave = t >> 6, lane = t & 63;

    // XCD-aware swizzle: launch id -> work id, contiguous chunk per XCD
    const int nwg = gridDim.x * gridDim.y;
    int bid = blockIdx.y * gridDim.x + blockIdx.x;
    bid = (bid & 7) * (nwg >> 3) + (bid >> 3);
    const int bx = bid % gridDim.x, by = bid / gridDim.x;
    const int m0 = by * BM, n0 = bx * BN;

    const int wmrow = (BN >= 128) ? (wave & 1) * 64 : (BM == 128 ? wave * 32 : wave * 16);
    const int wnrow = (BN == 256) ? (wave >> 1) * 128 : ((BN == 128) ? (wave >> 1) * 64 : 0);
    const int mlane = lane & 15, quad = lane >> 4;

    floatx4 acc[MI][NI];
#pragma unroll
    for (int mi = 0; mi < MI; ++mi)
#pragma unroll
        for (int ni = 0; ni < NI; ++ni) {
            floatx4 z = {0.0f, 0.0f, 0.0f, 0.0f};
            acc[mi][ni] = z;
        }

    for (int k0 = 0; k0 < K; k0 += 64) {
        __syncthreads();
#pragma unroll
        for (int j = 0; j < CHA / 128; ++j) {
            const int c = j * 256 + t;
            const int hh = c / CHA, cc = c % CHA;
            load16_lds(A + (size_t)(m0 + (cc >> 2)) * K + k0 + hh * 32 + (cc & 3) * 8,
                       &As[hh][cc * 8]);
        }
#pragma unroll
        for (int j = 0; j < CHB / 128; ++j) {
            const int c = j * 256 + t;
            const int hh = c / CHB, cc = c % CHB;
            load16_lds(Bt + (size_t)(n0 + (cc >> 2)) * K + k0 + hh * 32 + (cc & 3) * 8,
                       &Bs[hh][cc * 8]);
        }
        __syncthreads();
#pragma unroll
        for (int hh = 0; hh < 2; ++hh) {
            short8v a[MI], b[NI];
#pragma unroll
            for (int mi = 0; mi < MI; ++mi)
                a[mi] = *(const short8v*)&As[hh][(wmrow + mi * 16 + mlane) * 32 + quad * 8];
#pragma unroll
            for (int ni = 0; ni < NI; ++ni)
                b[ni] = *(const short8v*)&Bs[hh][(wnrow + ni * 16 + mlane) * 32 + quad * 8];
#pragma unroll
            for (int mi = 0; mi < MI; ++mi)
#pragma unroll
                for (int ni = 0; ni < NI; ++ni) {
                    if (SWAP)
                        acc[mi][ni] = __builtin_amdgcn_mfma_f32_16x16x32_bf16(b[ni], a[mi], acc[mi][ni], 0, 0, 0);
                    else
                        acc[mi][ni] = __builtin_amdgcn_mfma_f32_16x16x32_bf16(a[mi], b[ni], acc[mi][ni], 0, 0, 0);
                }
        }
    }

    if (SWAP) {
#pragma unroll
        for (int mi = 0; mi < MI; ++mi) {
            const int row = m0 + wmrow + mi * 16 + mlane;
#pragma unroll
            for (int ni = 0; ni < NI; ++ni) {
                const int col0 = n0 + wnrow + ni * 16 + quad * 4;
                const float4 bv4 = *(const float4*)(bias + col0);
                float v0 = acc[mi][ni][0] + bv4.x;
                float v1 = acc[mi][ni][1] + bv4.y;
                float v2 = acc[mi][ni][2] + bv4.z;
                float v3 = acc[mi][ni][3] + bv4.w;
                if (RES) {
                    const float4 r4 = *(const float4*)(res + (size_t)row * N + col0);
                    v0 += r4.x; v1 += r4.y; v2 += r4.z; v3 += r4.w;
                }
                if (GELU) {
                    v0 = 0.5f * v0 * (1.0f + erff(v0 * 0.70710678118654752f));
                    v1 = 0.5f * v1 * (1.0f + erff(v1 * 0.70710678118654752f));
                    v2 = 0.5f * v2 * (1.0f + erff(v2 * 0.70710678118654752f));
                    v3 = 0.5f * v3 * (1.0f + erff(v3 * 0.70710678118654752f));
                }
                if (OBF16) {
                    uint2 pk;
                    pk.x = pack2bf(v0, v1);
                    pk.y = pack2bf(v2, v3);
                    *(uint2*)((unsigned short*)Cv + (size_t)row * N + col0) = pk;
                } else {
                    float4 o4 = {v0, v1, v2, v3};
                    *(float4*)((float*)Cv + (size_t)row * N + col0) = o4;
                }
            }
        }
    } else {
#pragma unroll
        for (int mi = 0; mi < MI; ++mi) {
#pragma unroll
            for (int ni = 0; ni < NI; ++ni) {
                const int col = n0 + wnrow + ni * 16 + mlane;
                const float bv = bias[col];
                const int row0 = m0 + wmrow + mi * 16 + quad * 4;
                if (VOUT && col >= 2048) {
                    const int vd = col - 2048;
                    const int bb = row0 >> 11, ss = row0 & 2047;
                    uint2 pk;
                    pk.x = pack2bf(acc[mi][ni][0] + bv, acc[mi][ni][1] + bv);
                    pk.y = pack2bf(acc[mi][ni][2] + bv, acc[mi][ni][3] + bv);
                    *(uint2*)(vtout + ((size_t)(bb * NH + (vd >> 6)) * DHEAD + (vd & 63)) * SEQ + ss) = pk;
                } else {
#pragma unroll
                    for (int rg = 0; rg < 4; ++rg) {
                        const int row = row0 + rg;
                        float v = acc[mi][ni][rg] + bv;
                        if (RES) v += res[(size_t)row * N + col];
                        if (GELU) v = 0.5f * v * (1.0f + erff(v * 0.70710678118654752f));
                        if (QSCALE && col < 1024) v *= 0.18033688011112042f;  // 0.125*log2(e)
                        if (OBF16)
                            ((unsigned short*)Cv)[(size_t)row * N + col] = f2bf(v);
                        else
                            ((float*)Cv)[(size_t)row * N + col] = v;
                    }
                }
            }
        }
    }
}

// ---------------- MFMA flash attention (causal), 64-key windows ----------------
__global__ __launch_bounds__(512, 4) void attn_kernel(const unsigned short* __restrict__ qkv,
                                                      const unsigned short* __restrict__ vt,
                                                      unsigned short* __restrict__ o) {
    const int g = blockIdx.x;
    const int qt = (g < 256) ? (15 - (g >> 5)) : ((g - 256) >> 5);
    const int hb = g & 31;
    const int h = hb & 15, b = hb >> 4;
    const int t = threadIdx.x;
    const int wave = t >> 6, lane = t & 63;
    const int mlane = lane & 15, quad = lane >> 4;
    const int msw = mlane & 7;
    const int wq0 = qt * 128 + wave * 16;
    const size_t bS = (size_t)b * SEQ;

    __shared__ unsigned short Ks[64][64];
    __shared__ unsigned short Vs[64][64];
    __shared__ __align__(16) unsigned short plds[8][16][64];

    short8v qf0, qf1;
    {
        const unsigned short* qrow = qkv + (bS + wq0 + mlane) * QKVD + h * DHEAD;
        qf0 = *(const short8v*)(qrow + quad * 8);
        qf1 = *(const short8v*)(qrow + 32 + quad * 8);
    }

    const unsigned short* kbase = qkv + bS * QKVD + 1024 + h * DHEAD;
    const unsigned short* vbase = vt + ((size_t)(b * NH + h)) * DHEAD * SEQ;

    const int sr = t >> 3, sc = t & 7;
    const int ssw = (sc ^ (sr & 7)) * 8;
    const unsigned short* kg = kbase + (size_t)sr * QKVD + sc * 8;
    const unsigned short* vg = vbase + (size_t)sr * SEQ + sc * 8;

    floatx4 ot[4];
#pragma unroll
    for (int mt = 0; mt < 4; ++mt) { floatx4 z = {0, 0, 0, 0}; ot[mt] = z; }
    float m_r = -INFINITY, l_r = 0.0f;

    const int kend = wq0 + 16;
    const int kmax = qt * 128 + 128;

    uint4 kr = *(const uint4*)kg;
    uint4 vr = *(const uint4*)vg;

    for (int k0 = 0; k0 < kmax; k0 += 64) {
        *(uint4*)&Ks[sr][ssw] = kr;
        *(uint4*)&Vs[sr][ssw] = vr;
        __syncthreads();
        if (k0 + 64 < kmax) {
            kr = *(const uint4*)(kg + (size_t)(k0 + 64) * QKVD);
            vr = *(const uint4*)(vg + (k0 + 64));
        }
        if (k0 < kend) {
            floatx4 st[4];
#pragma unroll
            for (int kt = 0; kt < 4; ++kt) {
                if (k0 + kt * 16 < kend) {
                    short8v kfa = *(const short8v*)&Ks[kt * 16 + mlane][(quad ^ msw) * 8];
                    short8v kfb = *(const short8v*)&Ks[kt * 16 + mlane][((quad + 4) ^ msw) * 8];
                    floatx4 z = {0, 0, 0, 0};
                    st[kt] = __builtin_amdgcn_mfma_f32_16x16x32_bf16(kfa, qf0, z, 0, 0, 0);
                    st[kt] = __builtin_amdgcn_mfma_f32_16x16x32_bf16(kfb, qf1, st[kt], 0, 0, 0);
                } else {
                    floatx4 mz = {-1e30f, -1e30f, -1e30f, -1e30f};
                    st[kt] = mz;
                }
            }
            if (k0 + 64 >= kend) {
#pragma unroll
                for (int kt = 0; kt < 4; ++kt)
#pragma unroll
                    for (int rg = 0; rg < 4; ++rg)
                        if (k0 + kt * 16 + quad * 4 + rg > wq0 + mlane)
                            st[kt][rg] = -1e30f;
            }
            float tm = st[0][0];
#pragma unroll
            for (int kt = 0; kt < 4; ++kt)
#pragma unroll
                for (int rg = 0; rg < 4; ++rg) tm = fmaxf(tm, st[kt][rg]);
            tm = fmaxf(tm, __shfl_xor(tm, 16));
            tm = fmaxf(tm, __shfl_xor(tm, 32));
            if (!__all(tm <= m_r + 8.0f)) {
                const float newm = fmaxf(m_r, tm);
                const float alpha = exp2f(m_r - newm);
                l_r *= alpha;
#pragma unroll
                for (int mt = 0; mt < 4; ++mt)
#pragma unroll
                    for (int rg = 0; rg < 4; ++rg) ot[mt][rg] *= alpha;
                m_r = newm;
            }
            float p[4][4], psum = 0.0f;
#pragma unroll
            for (int kt = 0; kt < 4; ++kt)
#pragma unroll
                for (int rg = 0; rg < 4; ++rg) {
                    p[kt][rg] = exp2f(st[kt][rg] - m_r);
                    psum += p[kt][rg];
                }
            psum += __shfl_xor(psum, 16);
            psum += __shfl_xor(psum, 32);
            l_r += psum;
            char* prow = (char*)&plds[wave][mlane][0];
#pragma unroll
            for (int kt = 0; kt < 4; ++kt) {
                uint2 pk;
                pk.x = pack2bf(p[kt][0], p[kt][1]);
                pk.y = pack2bf(p[kt][2], p[kt][3]);
                *(uint2*)(prow + ((kt * 32 + quad * 8) ^ (msw << 4))) = pk;
            }
#pragma unroll
            for (int kh = 0; kh < 2; ++kh) {
                if (k0 + kh * 32 < kend) {
                    short8v vf[4];
#pragma unroll
                    for (int mt = 0; mt < 4; ++mt)
                        vf[mt] = *(const short8v*)&Vs[mt * 16 + mlane][(((kh * 4 + quad) ^ msw)) * 8];
                    short8v pf = *(const short8v*)(prow + (((kh * 4 + quad) ^ msw) << 4));
#pragma unroll
                    for (int mt = 0; mt < 4; ++mt)
                        ot[mt] = __builtin_amdgcn_mfma_f32_16x16x32_bf16(vf[mt], pf, ot[mt], 0, 0, 0);
                }
            }
        }
        __syncthreads();
    }

    const float inv = 1.0f / l_r;
    unsigned short* orow = o + (bS + wq0 + mlane) * BDIM + h * DHEAD;
#pragma unroll
    for (int mt = 0; mt < 4; ++mt) {
        uint2 pk;
        pk.x = pack2bf(ot[mt][0] * inv, ot[mt][1] * inv);
        pk.y = pack2bf(ot[mt][2] * inv, ot[mt][3] * inv);
        *(uint2*)(orow + mt * 16 + quad * 4) = pk;
    }
}

extern "C" void kernel_launch(void* const* d_in, const int* in_sizes, int n_in,
                              void* d_out, int out_size, void* d_ws, size_t ws_size,
                              hipStream_t stream) {
    const int M = 2 * SEQ;  // 4096

    const float* x = (const float*)d_in[0];
    const float* ln1_g = (const float*)d_in[1];
    const float* ln1_b = (const float*)d_in[2];
    const float* wq = (const float*)d_in[3];
    const float* bq = (const float*)d_in[4];
    const float* wk = (const float*)d_in[5];
    const float* bk = (const float*)d_in[6];
    const float* wv = (const float*)d_in[7];
    const float* bv = (const float*)d_in[8];
    const float* wo = (const float*)d_in[9];
    const float* bo = (const float*)d_in[10];
    const float* ln2_g = (const float*)d_in[11];
    const float* ln2_b = (const float*)d_in[12];
    const float* w1 = (const float*)d_in[13];
    const float* b1 = (const float*)d_in[14];
    const float* w2 = (const float*)d_in[15];
    const float* b2 = (const float*)d_in[16];

    char* wsb = (char*)d_ws;
    unsigned short* qkv = (unsigned short*)wsb;                    // [M][3072]
    unsigned short* ffn = (unsigned short*)wsb;                    // [M][4096] (later)
    unsigned short* vt = (unsigned short*)(wsb + (24u << 20));     // [32][64][2048]
    unsigned short* hbuf = (unsigned short*)(wsb + (32u << 20));   // h then o
    float* add1 = (float*)(wsb + (40u << 20));
    unsigned short* h2 = (unsigned short*)(wsb + (56u << 20));
    unsigned short* qkvT = (unsigned short*)(wsb + (64u << 20));
    unsigned short* woT = (unsigned short*)(wsb + (70u << 20));
    unsigned short* w1T = (unsigned short*)(wsb + (72u << 20));
    unsigned short* w2T = (unsigned short*)(wsb + (80u << 20));
    float* bqkv = (float*)(wsb + (88u << 20));

    // 0. weight convert+transpose (one launch), bias concat
    transpose_all<<<12288, 256, 0, stream>>>(wq, wk, wv, wo, w1, w2, qkvT, woT, w1T, w2T);
    concat_bias<<<12, 256, 0, stream>>>(bq, bk, bv, bqkv);

    // 1. h = LN1(x) -> bf16
    ln_kernel<<<M, 256, 0, stream>>>(x, ln1_g, ln1_b, hbuf);

    // 2. qkv = h @ [wq|wk|wv] + bias; Q pre-scaled 0.125*log2e; V transposed to vt
    mfma_gemm<128, 256, 0, 0, 1, 1, 1, 0><<<dim3(QKVD / 256, M / 128), 256, 0, stream>>>(
        hbuf, qkvT, bqkv, nullptr, qkv, vt, M, QKVD, 1024);

    // 3. o = causal_attention(qkv, vt) -> hbuf
    attn_kernel<<<512, 512, 0, stream>>>(qkv, vt, hbuf);

    // 4. add1 = o @ wo + bo + x (fp32), wide epilogue; BM=64 (N=1024 shape)
    mfma_gemm<64, 64, 1, 0, 0, 0, 0, 1><<<dim3(1024 / 64, M / 64), 256, 0, stream>>>(
        hbuf, woT, bo, x, add1, nullptr, M, 1024, 1024);

    // 5. h2 = LN2(add1) -> bf16
    ln_kernel<<<M, 256, 0, stream>>>(add1, ln2_g, ln2_b, h2);

    // 6. ffn = gelu(h2 @ w1 + b1) -> bf16 — 8-wave deep-pipelined 256x256 kernel
    mfma_gemm8<1><<<dim3(FDIM / 256, M / 256), 512, 0, stream>>>(
        h2, w1T, b1, ffn, M, FDIM, 1024);

    // 7. out = ffn @ w2 + b2 + add1 -> fp32 d_out; BM=64 (N=1024 shape)
    mfma_gemm<64, 64, 1, 0, 0, 0, 0, 1><<<dim3(1024 / 64, M / 64), 256, 0, stream>>>(
        ffn, w2T, b2, add1, (float*)d_out, nullptr, M, 1024, FDIM);
}

// Round 8
// 359.401 us; speedup vs baseline: 1.1840x; 1.1840x over previous
//
#include <hip/hip_runtime.h>
#include <hip/hip_bf16.h>

// GPT2 block fwd: B=2,S=2048,D=1024,H=16,DH=64,F=4096. fp32 in/out, bf16 MFMA.
// ws layout (bytes):
//   [0,24M)   qkv bf16 [4096][3072]  (V cols unused; slot reused by ffn 32MB)
//   [24M,32M) vt bf16 [32 bh][64 d][2048 s]  (written by QKV GEMM epilogue)
//   [32M,40M) hbuf bf16: h (LN1 out), later attention output o
//   [40M,56M) add1 fp32 [4096][1024]
//   [56M,64M) h2 bf16
//   [64M,70M) qkvT bf16 | [70M,72M) woT | [72M,80M) w1T | [80M,88M) w2T
//   [88M,..)  bias_qkv fp32 [3072]
// total ~88MB.

#define BDIM 1024
#define SEQ 2048
#define NH 16
#define DHEAD 64
#define FDIM 4096
#define QKVD 3072

typedef __attribute__((ext_vector_type(8))) short short8v;
typedef __attribute__((ext_vector_type(4))) float floatx4;

__device__ __forceinline__ unsigned short f2bf(float f) {
    unsigned int u = __float_as_uint(f);
    unsigned int r = u + 0x7FFFu + ((u >> 16) & 1u);
    return (unsigned short)(r >> 16);
}
__device__ __forceinline__ unsigned int pack2bf(float a, float b) {
    return (unsigned int)f2bf(a) | ((unsigned int)f2bf(b) << 16);
}

__device__ __forceinline__ void load16_lds(const unsigned short* g, short* l) {
    __builtin_amdgcn_global_load_lds((const __attribute__((address_space(1))) void*)g,
                                     (__attribute__((address_space(3))) void*)l, 16, 0, 0);
}

// ---------------- batched weight fp32 [K,N] -> bf16 [N,K] transpose ----------
__global__ __launch_bounds__(256) void transpose_all(const float* __restrict__ wq,
                                                     const float* __restrict__ wk,
                                                     const float* __restrict__ wv,
                                                     const float* __restrict__ wo,
                                                     const float* __restrict__ w1,
                                                     const float* __restrict__ w2,
                                                     unsigned short* __restrict__ qkvT,
                                                     unsigned short* __restrict__ woT,
                                                     unsigned short* __restrict__ w1T,
                                                     unsigned short* __restrict__ w2T) {
    const int g = blockIdx.x;
    const float* W;
    unsigned short* Wt;
    int K, N, tx, ty;
    if (g < 4096) {
        const int w = g >> 10, tile = g & 1023;
        tx = tile & 31; ty = tile >> 5; K = 1024; N = 1024;
        W = (w == 0) ? wq : (w == 1) ? wk : (w == 2) ? wv : wo;
        Wt = (w == 3) ? woT : qkvT + (size_t)w * 1024 * 1024;
    } else if (g < 8192) {
        const int tile = g - 4096;
        tx = tile & 127; ty = tile >> 7; K = 1024; N = 4096;
        W = w1; Wt = w1T;
    } else {
        const int tile = g - 8192;
        tx = tile & 31; ty = tile >> 5; K = 4096; N = 1024;
        W = w2; Wt = w2T;
    }
    __shared__ float tile[32][33];
    const int t = threadIdx.x;
    const int r = t >> 3, c4 = (t & 7) * 4;
    const int n0 = tx * 32, k0 = ty * 32;
    float4 p = *(const float4*)(W + (size_t)(k0 + r) * N + n0 + c4);
    tile[r][c4 + 0] = p.x;
    tile[r][c4 + 1] = p.y;
    tile[r][c4 + 2] = p.z;
    tile[r][c4 + 3] = p.w;
    __syncthreads();
    ushort4 ou;
    ou.x = f2bf(tile[c4 + 0][r]);
    ou.y = f2bf(tile[c4 + 1][r]);
    ou.z = f2bf(tile[c4 + 2][r]);
    ou.w = f2bf(tile[c4 + 3][r]);
    *(ushort4*)(Wt + (size_t)(n0 + r) * K + k0 + c4) = ou;
}

__global__ void concat_bias(const float* __restrict__ a, const float* __restrict__ b,
                            const float* __restrict__ c, float* __restrict__ out) {
    int i = blockIdx.x * 256 + threadIdx.x;
    out[i] = (i < 1024) ? a[i] : (i < 2048 ? b[i - 1024] : c[i - 2048]);
}

// ---------------- LayerNorm: fp32 in -> bf16 out ----------------
__global__ __launch_bounds__(256) void ln_kernel(const float* __restrict__ x,
                                                 const float* __restrict__ g,
                                                 const float* __restrict__ bb,
                                                 unsigned short* __restrict__ out) {
    const int row = blockIdx.x;
    const int t = threadIdx.x;
    const int c = t * 4;
    float4 p = *(const float4*)(x + (size_t)row * BDIM + c);
    float s = p.x + p.y + p.z + p.w;
    float sq = p.x * p.x + p.y * p.y + p.z * p.z + p.w * p.w;
    for (int off = 1; off < 64; off <<= 1) {
        s += __shfl_xor(s, off);
        sq += __shfl_xor(sq, off);
    }
    __shared__ float ssum[4], ssq[4];
    const int wave = t >> 6, lane = t & 63;
    if (lane == 0) { ssum[wave] = s; ssq[wave] = sq; }
    __syncthreads();
    s = ssum[0] + ssum[1] + ssum[2] + ssum[3];
    sq = ssq[0] + ssq[1] + ssq[2] + ssq[3];
    const float mean = s * (1.0f / BDIM);
    const float var = sq * (1.0f / BDIM) - mean * mean;
    const float rstd = rsqrtf(var + 1e-5f);
    float4 gg = *(const float4*)(g + c);
    float4 bv = *(const float4*)(bb + c);
    ushort4 o;
    o.x = f2bf((p.x - mean) * rstd * gg.x + bv.x);
    o.y = f2bf((p.y - mean) * rstd * gg.y + bv.y);
    o.z = f2bf((p.z - mean) * rstd * gg.z + bv.z);
    o.w = f2bf((p.w - mean) * rstd * gg.w + bv.w);
    *(ushort4*)(out + (size_t)row * BDIM + c) = o;
}

// ---------------- MFMA GEMM, 2-phase, parameterized BK ----------------
// Loop: stage all BK/32 K-halves -> sync -> compute all. Per-K-step cost model:
// compute C + ~200cy barrier drain; eff = C/(C+200). BK=128 on the deep/narrow
// GEMMs (wo/w2) halves barrier count: measured-model 63us (BK=64) -> ~51us.
// T1 XCD swizzle on linear block id (all grids divisible by 8) for L2 locality.
// Tile configs:
//   BM=128/BN=256: 4 waves 2x2, wave-tile 64x128 (MI=4,NI=8) — QKV/FFN1, BK=64.
//   BM=128/BN=64:  4 waves stacked, wave 32x64 (MI=2) — wo/w2, BK=128 (48KB).
// SWAP=1: MFMA operands swapped (b,a) -> thread holds one row, 4 consecutive
//   cols -> wide epilogue (float4/uint2 stores, float4 bias/res loads).
// SWAP=0 (QKV): original layout; VOUT packed-uint2 transposed V store, QSCALE.
// QSCALE: output cols < 1024 scaled by 0.125*log2(e) (exp2-domain softmax).
// VOUT: output cols >= 2048 (V of QKV) written transposed to vt[bh][d][s].
template <int BM, int BN, int BK, int RES, int GELU, int OBF16, int QSCALE = 0, int VOUT = 0, int SWAP = 1>
__global__ __launch_bounds__(256, (BN == 256) ? 2 : 3) void mfma_gemm(
        const unsigned short* __restrict__ A,
        const unsigned short* __restrict__ Bt,
        const float* __restrict__ bias,
        const float* __restrict__ res,
        void* __restrict__ Cv,
        unsigned short* __restrict__ vtout,
        int M, int N, int K) {
    constexpr int HH = BK / 32;       // 32-col halves per K-step
    constexpr int NI = (BN == 256) ? 8 : 4;
    constexpr int MI = (BN >= 128) ? 4 : (BM == 128 ? 2 : 1);
    constexpr int CHA = BM * 4;  // 16B-chunks per A 32-col half
    constexpr int CHB = BN * 4;  // 16B-chunks per B 32-col half
    __shared__ short As[HH][BM * 32];
    __shared__ short Bs[HH][BN * 32];
    const int t = threadIdx.x;
    const int wave = t >> 6, lane = t & 63;

    // XCD-aware swizzle: launch id -> work id, contiguous chunk per XCD
    const int nwg = gridDim.x * gridDim.y;
    int bid = blockIdx.y * gridDim.x + blockIdx.x;
    bid = (bid & 7) * (nwg >> 3) + (bid >> 3);
    const int bx = bid % gridDim.x, by = bid / gridDim.x;
    const int m0 = by * BM, n0 = bx * BN;

    const int wmrow = (BN >= 128) ? (wave & 1) * 64 : (BM == 128 ? wave * 32 : wave * 16);
    const int wnrow = (BN == 256) ? (wave >> 1) * 128 : ((BN == 128) ? (wave >> 1) * 64 : 0);
    const int mlane = lane & 15, quad = lane >> 4;

    floatx4 acc[MI][NI];
#pragma unroll
    for (int mi = 0; mi < MI; ++mi)
#pragma unroll
        for (int ni = 0; ni < NI; ++ni) {
            floatx4 z = {0.0f, 0.0f, 0.0f, 0.0f};
            acc[mi][ni] = z;
        }

    for (int k0 = 0; k0 < K; k0 += BK) {
        __syncthreads();
#pragma unroll
        for (int j = 0; j < HH * CHA / 256; ++j) {
            const int c = j * 256 + t;
            const int hh = c / CHA, cc = c % CHA;
            load16_lds(A + (size_t)(m0 + (cc >> 2)) * K + k0 + hh * 32 + (cc & 3) * 8,
                       &As[hh][cc * 8]);
        }
#pragma unroll
        for (int j = 0; j < HH * CHB / 256; ++j) {
            const int c = j * 256 + t;
            const int hh = c / CHB, cc = c % CHB;
            load16_lds(Bt + (size_t)(n0 + (cc >> 2)) * K + k0 + hh * 32 + (cc & 3) * 8,
                       &Bs[hh][cc * 8]);
        }
        __syncthreads();
#pragma unroll
        for (int hh = 0; hh < HH; ++hh) {
            short8v a[MI], b[NI];
#pragma unroll
            for (int mi = 0; mi < MI; ++mi)
                a[mi] = *(const short8v*)&As[hh][(wmrow + mi * 16 + mlane) * 32 + quad * 8];
#pragma unroll
            for (int ni = 0; ni < NI; ++ni)
                b[ni] = *(const short8v*)&Bs[hh][(wnrow + ni * 16 + mlane) * 32 + quad * 8];
#pragma unroll
            for (int mi = 0; mi < MI; ++mi)
#pragma unroll
                for (int ni = 0; ni < NI; ++ni) {
                    if (SWAP)
                        acc[mi][ni] = __builtin_amdgcn_mfma_f32_16x16x32_bf16(b[ni], a[mi], acc[mi][ni], 0, 0, 0);
                    else
                        acc[mi][ni] = __builtin_amdgcn_mfma_f32_16x16x32_bf16(a[mi], b[ni], acc[mi][ni], 0, 0, 0);
                }
        }
    }

    if (SWAP) {
        // thread holds row = m0+wmrow+mi*16+mlane, cols col0..col0+3 (wide stores)
#pragma unroll
        for (int mi = 0; mi < MI; ++mi) {
            const int row = m0 + wmrow + mi * 16 + mlane;
#pragma unroll
            for (int ni = 0; ni < NI; ++ni) {
                const int col0 = n0 + wnrow + ni * 16 + quad * 4;
                const float4 bv4 = *(const float4*)(bias + col0);
                float v0 = acc[mi][ni][0] + bv4.x;
                float v1 = acc[mi][ni][1] + bv4.y;
                float v2 = acc[mi][ni][2] + bv4.z;
                float v3 = acc[mi][ni][3] + bv4.w;
                if (RES) {
                    const float4 r4 = *(const float4*)(res + (size_t)row * N + col0);
                    v0 += r4.x; v1 += r4.y; v2 += r4.z; v3 += r4.w;
                }
                if (GELU) {
                    v0 = 0.5f * v0 * (1.0f + erff(v0 * 0.70710678118654752f));
                    v1 = 0.5f * v1 * (1.0f + erff(v1 * 0.70710678118654752f));
                    v2 = 0.5f * v2 * (1.0f + erff(v2 * 0.70710678118654752f));
                    v3 = 0.5f * v3 * (1.0f + erff(v3 * 0.70710678118654752f));
                }
                if (OBF16) {
                    uint2 pk;
                    pk.x = pack2bf(v0, v1);
                    pk.y = pack2bf(v2, v3);
                    *(uint2*)((unsigned short*)Cv + (size_t)row * N + col0) = pk;
                } else {
                    float4 o4 = {v0, v1, v2, v3};
                    *(float4*)((float*)Cv + (size_t)row * N + col0) = o4;
                }
            }
        }
    } else {
        // original layout: thread holds col = ...+mlane, rows row0..row0+3
#pragma unroll
        for (int mi = 0; mi < MI; ++mi) {
#pragma unroll
            for (int ni = 0; ni < NI; ++ni) {
                const int col = n0 + wnrow + ni * 16 + mlane;
                const float bv = bias[col];
                const int row0 = m0 + wmrow + mi * 16 + quad * 4;
                if (VOUT && col >= 2048) {
                    // V output, transposed: vt[(b*16+h)*64+d][s], 4 consecutive s packed
                    const int vd = col - 2048;
                    const int bb = row0 >> 11, ss = row0 & 2047;
                    uint2 pk;
                    pk.x = pack2bf(acc[mi][ni][0] + bv, acc[mi][ni][1] + bv);
                    pk.y = pack2bf(acc[mi][ni][2] + bv, acc[mi][ni][3] + bv);
                    *(uint2*)(vtout + ((size_t)(bb * NH + (vd >> 6)) * DHEAD + (vd & 63)) * SEQ + ss) = pk;
                } else {
#pragma unroll
                    for (int rg = 0; rg < 4; ++rg) {
                        const int row = row0 + rg;
                        float v = acc[mi][ni][rg] + bv;
                        if (RES) v += res[(size_t)row * N + col];
                        if (GELU) v = 0.5f * v * (1.0f + erff(v * 0.70710678118654752f));
                        if (QSCALE && col < 1024) v *= 0.18033688011112042f;  // 0.125*log2(e)
                        if (OBF16)
                            ((unsigned short*)Cv)[(size_t)row * N + col] = f2bf(v);
                        else
                            ((float*)Cv)[(size_t)row * N + col] = v;
                    }
                }
            }
        }
    }
}

// ---------------- MFMA flash attention (causal), 64-key windows ----------------
// 1D grid of 512 blocks x 512 threads (8 waves x 16 queries = 128 q/block).
// Block c (c<256) gets qt=15-(c>>5), block 256+c gets qt=(c>>5) -> co-resident
// pairs sum to constant work. Per 64-key window: stage K(64x64) + V^T(64x64) in
// LDS (16B-chunk XOR swizzle, conflict-free b128 reads), QK/PV MFMA with causal
// skip, exp2-domain online softmax (Q pre-scaled by 0.125*log2e in QKV GEMM)
// with deferred-max rescale (THR=8), P^T via per-wave swizzled LDS round-trip.
__global__ __launch_bounds__(512, 4) void attn_kernel(const unsigned short* __restrict__ qkv,
                                                      const unsigned short* __restrict__ vt,
                                                      unsigned short* __restrict__ o) {
    const int g = blockIdx.x;
    const int qt = (g < 256) ? (15 - (g >> 5)) : ((g - 256) >> 5);
    const int hb = g & 31;
    const int h = hb & 15, b = hb >> 4;
    const int t = threadIdx.x;
    const int wave = t >> 6, lane = t & 63;
    const int mlane = lane & 15, quad = lane >> 4;
    const int msw = mlane & 7;
    const int wq0 = qt * 128 + wave * 16;
    const size_t bS = (size_t)b * SEQ;

    __shared__ unsigned short Ks[64][64];
    __shared__ unsigned short Vs[64][64];
    __shared__ __align__(16) unsigned short plds[8][16][64];

    short8v qf0, qf1;
    {
        const unsigned short* qrow = qkv + (bS + wq0 + mlane) * QKVD + h * DHEAD;
        qf0 = *(const short8v*)(qrow + quad * 8);
        qf1 = *(const short8v*)(qrow + 32 + quad * 8);
    }

    const unsigned short* kbase = qkv + bS * QKVD + 1024 + h * DHEAD;
    const unsigned short* vbase = vt + ((size_t)(b * NH + h)) * DHEAD * SEQ;

    const int sr = t >> 3, sc = t & 7;
    const int ssw = (sc ^ (sr & 7)) * 8;
    const unsigned short* kg = kbase + (size_t)sr * QKVD + sc * 8;
    const unsigned short* vg = vbase + (size_t)sr * SEQ + sc * 8;

    floatx4 ot[4];
#pragma unroll
    for (int mt = 0; mt < 4; ++mt) { floatx4 z = {0, 0, 0, 0}; ot[mt] = z; }
    float m_r = -INFINITY, l_r = 0.0f;

    const int kend = wq0 + 16;
    const int kmax = qt * 128 + 128;

    uint4 kr = *(const uint4*)kg;
    uint4 vr = *(const uint4*)vg;

    for (int k0 = 0; k0 < kmax; k0 += 64) {
        *(uint4*)&Ks[sr][ssw] = kr;
        *(uint4*)&Vs[sr][ssw] = vr;
        __syncthreads();
        if (k0 + 64 < kmax) {
            kr = *(const uint4*)(kg + (size_t)(k0 + 64) * QKVD);
            vr = *(const uint4*)(vg + (k0 + 64));
        }
        if (k0 < kend) {
            floatx4 st[4];
#pragma unroll
            for (int kt = 0; kt < 4; ++kt) {
                if (k0 + kt * 16 < kend) {
                    short8v kfa = *(const short8v*)&Ks[kt * 16 + mlane][(quad ^ msw) * 8];
                    short8v kfb = *(const short8v*)&Ks[kt * 16 + mlane][((quad + 4) ^ msw) * 8];
                    floatx4 z = {0, 0, 0, 0};
                    st[kt] = __builtin_amdgcn_mfma_f32_16x16x32_bf16(kfa, qf0, z, 0, 0, 0);
                    st[kt] = __builtin_amdgcn_mfma_f32_16x16x32_bf16(kfb, qf1, st[kt], 0, 0, 0);
                } else {
                    floatx4 mz = {-1e30f, -1e30f, -1e30f, -1e30f};
                    st[kt] = mz;
                }
            }
            if (k0 + 64 >= kend) {
#pragma unroll
                for (int kt = 0; kt < 4; ++kt)
#pragma unroll
                    for (int rg = 0; rg < 4; ++rg)
                        if (k0 + kt * 16 + quad * 4 + rg > wq0 + mlane)
                            st[kt][rg] = -1e30f;
            }
            float tm = st[0][0];
#pragma unroll
            for (int kt = 0; kt < 4; ++kt)
#pragma unroll
                for (int rg = 0; rg < 4; ++rg) tm = fmaxf(tm, st[kt][rg]);
            tm = fmaxf(tm, __shfl_xor(tm, 16));
            tm = fmaxf(tm, __shfl_xor(tm, 32));
            if (!__all(tm <= m_r + 8.0f)) {
                const float newm = fmaxf(m_r, tm);
                const float alpha = exp2f(m_r - newm);
                l_r *= alpha;
#pragma unroll
                for (int mt = 0; mt < 4; ++mt)
#pragma unroll
                    for (int rg = 0; rg < 4; ++rg) ot[mt][rg] *= alpha;
                m_r = newm;
            }
            float p[4][4], psum = 0.0f;
#pragma unroll
            for (int kt = 0; kt < 4; ++kt)
#pragma unroll
                for (int rg = 0; rg < 4; ++rg) {
                    p[kt][rg] = exp2f(st[kt][rg] - m_r);
                    psum += p[kt][rg];
                }
            psum += __shfl_xor(psum, 16);
            psum += __shfl_xor(psum, 32);
            l_r += psum;
            char* prow = (char*)&plds[wave][mlane][0];
#pragma unroll
            for (int kt = 0; kt < 4; ++kt) {
                uint2 pk;
                pk.x = pack2bf(p[kt][0], p[kt][1]);
                pk.y = pack2bf(p[kt][2], p[kt][3]);
                *(uint2*)(prow + ((kt * 32 + quad * 8) ^ (msw << 4))) = pk;
            }
#pragma unroll
            for (int kh = 0; kh < 2; ++kh) {
                if (k0 + kh * 32 < kend) {
                    short8v vf[4];
#pragma unroll
                    for (int mt = 0; mt < 4; ++mt)
                        vf[mt] = *(const short8v*)&Vs[mt * 16 + mlane][(((kh * 4 + quad) ^ msw)) * 8];
                    short8v pf = *(const short8v*)(prow + (((kh * 4 + quad) ^ msw) << 4));
#pragma unroll
                    for (int mt = 0; mt < 4; ++mt)
                        ot[mt] = __builtin_amdgcn_mfma_f32_16x16x32_bf16(vf[mt], pf, ot[mt], 0, 0, 0);
                }
            }
        }
        __syncthreads();
    }

    const float inv = 1.0f / l_r;
    unsigned short* orow = o + (bS + wq0 + mlane) * BDIM + h * DHEAD;
#pragma unroll
    for (int mt = 0; mt < 4; ++mt) {
        uint2 pk;
        pk.x = pack2bf(ot[mt][0] * inv, ot[mt][1] * inv);
        pk.y = pack2bf(ot[mt][2] * inv, ot[mt][3] * inv);
        *(uint2*)(orow + mt * 16 + quad * 4) = pk;
    }
}

extern "C" void kernel_launch(void* const* d_in, const int* in_sizes, int n_in,
                              void* d_out, int out_size, void* d_ws, size_t ws_size,
                              hipStream_t stream) {
    const int M = 2 * SEQ;  // 4096

    const float* x = (const float*)d_in[0];
    const float* ln1_g = (const float*)d_in[1];
    const float* ln1_b = (const float*)d_in[2];
    const float* wq = (const float*)d_in[3];
    const float* bq = (const float*)d_in[4];
    const float* wk = (const float*)d_in[5];
    const float* bk = (const float*)d_in[6];
    const float* wv = (const float*)d_in[7];
    const float* bv = (const float*)d_in[8];
    const float* wo = (const float*)d_in[9];
    const float* bo = (const float*)d_in[10];
    const float* ln2_g = (const float*)d_in[11];
    const float* ln2_b = (const float*)d_in[12];
    const float* w1 = (const float*)d_in[13];
    const float* b1 = (const float*)d_in[14];
    const float* w2 = (const float*)d_in[15];
    const float* b2 = (const float*)d_in[16];

    char* wsb = (char*)d_ws;
    unsigned short* qkv = (unsigned short*)wsb;                    // [M][3072]
    unsigned short* ffn = (unsigned short*)wsb;                    // [M][4096] (later)
    unsigned short* vt = (unsigned short*)(wsb + (24u << 20));     // [32][64][2048]
    unsigned short* hbuf = (unsigned short*)(wsb + (32u << 20));   // h then o
    float* add1 = (float*)(wsb + (40u << 20));
    unsigned short* h2 = (unsigned short*)(wsb + (56u << 20));
    unsigned short* qkvT = (unsigned short*)(wsb + (64u << 20));
    unsigned short* woT = (unsigned short*)(wsb + (70u << 20));
    unsigned short* w1T = (unsigned short*)(wsb + (72u << 20));
    unsigned short* w2T = (unsigned short*)(wsb + (80u << 20));
    float* bqkv = (float*)(wsb + (88u << 20));

    // 0. weight convert+transpose (one launch), bias concat
    transpose_all<<<12288, 256, 0, stream>>>(wq, wk, wv, wo, w1, w2, qkvT, woT, w1T, w2T);
    concat_bias<<<12, 256, 0, stream>>>(bq, bk, bv, bqkv);

    // 1. h = LN1(x) -> bf16
    ln_kernel<<<M, 256, 0, stream>>>(x, ln1_g, ln1_b, hbuf);

    // 2. qkv = h @ [wq|wk|wv] + bias; Q pre-scaled 0.125*log2e; V transposed to vt
    mfma_gemm<128, 256, 64, 0, 0, 1, 1, 1, 0><<<dim3(QKVD / 256, M / 128), 256, 0, stream>>>(
        hbuf, qkvT, bqkv, nullptr, qkv, vt, M, QKVD, 1024);

    // 3. o = causal_attention(qkv, vt) -> hbuf
    attn_kernel<<<512, 512, 0, stream>>>(qkv, vt, hbuf);

    // 4. add1 = o @ wo + bo + x (fp32); BK=128 (halved barrier count)
    mfma_gemm<128, 64, 128, 1, 0, 0, 0, 0, 1><<<dim3(1024 / 64, M / 128), 256, 0, stream>>>(
        hbuf, woT, bo, x, add1, nullptr, M, 1024, 1024);

    // 5. h2 = LN2(add1) -> bf16
    ln_kernel<<<M, 256, 0, stream>>>(add1, ln2_g, ln2_b, h2);

    // 6. ffn = gelu(h2 @ w1 + b1) -> bf16 — proven 2-phase BN=256
    mfma_gemm<128, 256, 64, 0, 1, 1, 0, 0, 1><<<dim3(FDIM / 256, M / 128), 256, 0, stream>>>(
        h2, w1T, b1, nullptr, ffn, nullptr, M, FDIM, 1024);

    // 7. out = ffn @ w2 + b2 + add1 -> fp32 d_out; BK=128
    mfma_gemm<128, 64, 128, 1, 0, 0, 0, 0, 1><<<dim3(1024 / 64, M / 128), 256, 0, stream>>>(
        ffn, w2T, b2, add1, (float*)d_out, nullptr, M, 1024, FDIM);
}

// Round 9
// 350.103 us; speedup vs baseline: 1.2154x; 1.0266x over previous
//
#include <hip/hip_runtime.h>
#include <hip/hip_bf16.h>

// GPT2 block fwd: B=2,S=2048,D=1024,H=16,DH=64,F=4096. fp32 in/out, bf16 MFMA.
// ws layout (bytes):
//   [0,24M)   qkv bf16 [4096][3072]  (V cols unused; slot reused by ffn 32MB)
//   [24M,32M) vt bf16 [32 bh][64 d][2048 s]  (written by QKV GEMM epilogue)
//   [32M,40M) hbuf bf16: h (LN1 out), later attention output o
//   [40M,56M) add1 fp32 [4096][1024]
//   [56M,64M) h2 bf16
//   [64M,70M) qkvT bf16 | [70M,72M) woT | [72M,80M) w1T | [80M,88M) w2T
//   [88M,..)  bias_qkv fp32 [3072]
// total ~88MB.

#define BDIM 1024
#define SEQ 2048
#define NH 16
#define DHEAD 64
#define FDIM 4096
#define QKVD 3072

typedef __attribute__((ext_vector_type(8))) short short8v;
typedef __attribute__((ext_vector_type(4))) float floatx4;

__device__ __forceinline__ unsigned short f2bf(float f) {
    unsigned int u = __float_as_uint(f);
    unsigned int r = u + 0x7FFFu + ((u >> 16) & 1u);
    return (unsigned short)(r >> 16);
}
__device__ __forceinline__ unsigned int pack2bf(float a, float b) {
    return (unsigned int)f2bf(a) | ((unsigned int)f2bf(b) << 16);
}
// hot-path pair convert: 1 instruction instead of ~7 integer VALU ops
__device__ __forceinline__ unsigned int cvtpk2(float a, float b) {
    unsigned int r;
    asm("v_cvt_pk_bf16_f32 %0, %1, %2" : "=v"(r) : "v"(a), "v"(b));
    return r;
}

__device__ __forceinline__ void load16_lds(const unsigned short* g, short* l) {
    __builtin_amdgcn_global_load_lds((const __attribute__((address_space(1))) void*)g,
                                     (__attribute__((address_space(3))) void*)l, 16, 0, 0);
}

// ---------------- batched weight fp32 [K,N] -> bf16 [N,K] transpose ----------
__global__ __launch_bounds__(256) void transpose_all(const float* __restrict__ wq,
                                                     const float* __restrict__ wk,
                                                     const float* __restrict__ wv,
                                                     const float* __restrict__ wo,
                                                     const float* __restrict__ w1,
                                                     const float* __restrict__ w2,
                                                     unsigned short* __restrict__ qkvT,
                                                     unsigned short* __restrict__ woT,
                                                     unsigned short* __restrict__ w1T,
                                                     unsigned short* __restrict__ w2T) {
    const int g = blockIdx.x;
    const float* W;
    unsigned short* Wt;
    int K, N, tx, ty;
    if (g < 4096) {
        const int w = g >> 10, tile = g & 1023;
        tx = tile & 31; ty = tile >> 5; K = 1024; N = 1024;
        W = (w == 0) ? wq : (w == 1) ? wk : (w == 2) ? wv : wo;
        Wt = (w == 3) ? woT : qkvT + (size_t)w * 1024 * 1024;
    } else if (g < 8192) {
        const int tile = g - 4096;
        tx = tile & 127; ty = tile >> 7; K = 1024; N = 4096;
        W = w1; Wt = w1T;
    } else {
        const int tile = g - 8192;
        tx = tile & 31; ty = tile >> 5; K = 4096; N = 1024;
        W = w2; Wt = w2T;
    }
    __shared__ float tile[32][33];
    const int t = threadIdx.x;
    const int r = t >> 3, c4 = (t & 7) * 4;
    const int n0 = tx * 32, k0 = ty * 32;
    float4 p = *(const float4*)(W + (size_t)(k0 + r) * N + n0 + c4);
    tile[r][c4 + 0] = p.x;
    tile[r][c4 + 1] = p.y;
    tile[r][c4 + 2] = p.z;
    tile[r][c4 + 3] = p.w;
    __syncthreads();
    ushort4 ou;
    ou.x = f2bf(tile[c4 + 0][r]);
    ou.y = f2bf(tile[c4 + 1][r]);
    ou.z = f2bf(tile[c4 + 2][r]);
    ou.w = f2bf(tile[c4 + 3][r]);
    *(ushort4*)(Wt + (size_t)(n0 + r) * K + k0 + c4) = ou;
}

__global__ void concat_bias(const float* __restrict__ a, const float* __restrict__ b,
                            const float* __restrict__ c, float* __restrict__ out) {
    int i = blockIdx.x * 256 + threadIdx.x;
    out[i] = (i < 1024) ? a[i] : (i < 2048 ? b[i - 1024] : c[i - 2048]);
}

// ---------------- LayerNorm: fp32 in -> bf16 out ----------------
__global__ __launch_bounds__(256) void ln_kernel(const float* __restrict__ x,
                                                 const float* __restrict__ g,
                                                 const float* __restrict__ bb,
                                                 unsigned short* __restrict__ out) {
    const int row = blockIdx.x;
    const int t = threadIdx.x;
    const int c = t * 4;
    float4 p = *(const float4*)(x + (size_t)row * BDIM + c);
    float s = p.x + p.y + p.z + p.w;
    float sq = p.x * p.x + p.y * p.y + p.z * p.z + p.w * p.w;
    for (int off = 1; off < 64; off <<= 1) {
        s += __shfl_xor(s, off);
        sq += __shfl_xor(sq, off);
    }
    __shared__ float ssum[4], ssq[4];
    const int wave = t >> 6, lane = t & 63;
    if (lane == 0) { ssum[wave] = s; ssq[wave] = sq; }
    __syncthreads();
    s = ssum[0] + ssum[1] + ssum[2] + ssum[3];
    sq = ssq[0] + ssq[1] + ssq[2] + ssq[3];
    const float mean = s * (1.0f / BDIM);
    const float var = sq * (1.0f / BDIM) - mean * mean;
    const float rstd = rsqrtf(var + 1e-5f);
    float4 gg = *(const float4*)(g + c);
    float4 bv = *(const float4*)(bb + c);
    ushort4 o;
    o.x = f2bf((p.x - mean) * rstd * gg.x + bv.x);
    o.y = f2bf((p.y - mean) * rstd * gg.y + bv.y);
    o.z = f2bf((p.z - mean) * rstd * gg.z + bv.z);
    o.w = f2bf((p.w - mean) * rstd * gg.w + bv.w);
    *(ushort4*)(out + (size_t)row * BDIM + c) = o;
}

// ---------------- MFMA GEMM, 2-phase, parameterized BK ----------------
// Loop: stage all BK/32 K-halves -> sync -> compute all. Per-K-step cost model:
// compute C + ~200cy barrier drain; eff = C/(C+200). BK=128 on the deep/narrow
// GEMMs (wo/w2) halves barrier count (validated r8: w2 left top-5).
// T1 XCD swizzle on linear block id (all grids divisible by 8) for L2 locality.
// Tile configs:
//   BM=128/BN=256: 4 waves 2x2, wave-tile 64x128 (MI=4,NI=8) — QKV/FFN1, BK=64.
//   BM=128/BN=64:  4 waves stacked, wave 32x64 (MI=2) — wo/w2, BK=128 (48KB).
// SWAP=1: MFMA operands swapped (b,a) -> thread holds one row, 4 consecutive
//   cols -> wide epilogue (float4/uint2 stores, float4 bias/res loads).
// SWAP=0 (QKV): original layout; VOUT packed-uint2 transposed V store, QSCALE.
// QSCALE: output cols < 1024 scaled by 0.125*log2(e) (exp2-domain softmax).
// VOUT: output cols >= 2048 (V of QKV) written transposed to vt[bh][d][s].
template <int BM, int BN, int BK, int RES, int GELU, int OBF16, int QSCALE = 0, int VOUT = 0, int SWAP = 1>
__global__ __launch_bounds__(256, (BN == 256) ? 2 : 3) void mfma_gemm(
        const unsigned short* __restrict__ A,
        const unsigned short* __restrict__ Bt,
        const float* __restrict__ bias,
        const float* __restrict__ res,
        void* __restrict__ Cv,
        unsigned short* __restrict__ vtout,
        int M, int N, int K) {
    constexpr int HH = BK / 32;       // 32-col halves per K-step
    constexpr int NI = (BN == 256) ? 8 : 4;
    constexpr int MI = (BN >= 128) ? 4 : (BM == 128 ? 2 : 1);
    constexpr int CHA = BM * 4;  // 16B-chunks per A 32-col half
    constexpr int CHB = BN * 4;  // 16B-chunks per B 32-col half
    __shared__ short As[HH][BM * 32];
    __shared__ short Bs[HH][BN * 32];
    const int t = threadIdx.x;
    const int wave = t >> 6, lane = t & 63;

    // XCD-aware swizzle: launch id -> work id, contiguous chunk per XCD
    const int nwg = gridDim.x * gridDim.y;
    int bid = blockIdx.y * gridDim.x + blockIdx.x;
    bid = (bid & 7) * (nwg >> 3) + (bid >> 3);
    const int bx = bid % gridDim.x, by = bid / gridDim.x;
    const int m0 = by * BM, n0 = bx * BN;

    const int wmrow = (BN >= 128) ? (wave & 1) * 64 : (BM == 128 ? wave * 32 : wave * 16);
    const int wnrow = (BN == 256) ? (wave >> 1) * 128 : ((BN == 128) ? (wave >> 1) * 64 : 0);
    const int mlane = lane & 15, quad = lane >> 4;

    floatx4 acc[MI][NI];
#pragma unroll
    for (int mi = 0; mi < MI; ++mi)
#pragma unroll
        for (int ni = 0; ni < NI; ++ni) {
            floatx4 z = {0.0f, 0.0f, 0.0f, 0.0f};
            acc[mi][ni] = z;
        }

    for (int k0 = 0; k0 < K; k0 += BK) {
        __syncthreads();
#pragma unroll
        for (int j = 0; j < HH * CHA / 256; ++j) {
            const int c = j * 256 + t;
            const int hh = c / CHA, cc = c % CHA;
            load16_lds(A + (size_t)(m0 + (cc >> 2)) * K + k0 + hh * 32 + (cc & 3) * 8,
                       &As[hh][cc * 8]);
        }
#pragma unroll
        for (int j = 0; j < HH * CHB / 256; ++j) {
            const int c = j * 256 + t;
            const int hh = c / CHB, cc = c % CHB;
            load16_lds(Bt + (size_t)(n0 + (cc >> 2)) * K + k0 + hh * 32 + (cc & 3) * 8,
                       &Bs[hh][cc * 8]);
        }
        __syncthreads();
#pragma unroll
        for (int hh = 0; hh < HH; ++hh) {
            short8v a[MI], b[NI];
#pragma unroll
            for (int mi = 0; mi < MI; ++mi)
                a[mi] = *(const short8v*)&As[hh][(wmrow + mi * 16 + mlane) * 32 + quad * 8];
#pragma unroll
            for (int ni = 0; ni < NI; ++ni)
                b[ni] = *(const short8v*)&Bs[hh][(wnrow + ni * 16 + mlane) * 32 + quad * 8];
#pragma unroll
            for (int mi = 0; mi < MI; ++mi)
#pragma unroll
                for (int ni = 0; ni < NI; ++ni) {
                    if (SWAP)
                        acc[mi][ni] = __builtin_amdgcn_mfma_f32_16x16x32_bf16(b[ni], a[mi], acc[mi][ni], 0, 0, 0);
                    else
                        acc[mi][ni] = __builtin_amdgcn_mfma_f32_16x16x32_bf16(a[mi], b[ni], acc[mi][ni], 0, 0, 0);
                }
        }
    }

    if (SWAP) {
        // thread holds row = m0+wmrow+mi*16+mlane, cols col0..col0+3 (wide stores)
#pragma unroll
        for (int mi = 0; mi < MI; ++mi) {
            const int row = m0 + wmrow + mi * 16 + mlane;
#pragma unroll
            for (int ni = 0; ni < NI; ++ni) {
                const int col0 = n0 + wnrow + ni * 16 + quad * 4;
                const float4 bv4 = *(const float4*)(bias + col0);
                float v0 = acc[mi][ni][0] + bv4.x;
                float v1 = acc[mi][ni][1] + bv4.y;
                float v2 = acc[mi][ni][2] + bv4.z;
                float v3 = acc[mi][ni][3] + bv4.w;
                if (RES) {
                    const float4 r4 = *(const float4*)(res + (size_t)row * N + col0);
                    v0 += r4.x; v1 += r4.y; v2 += r4.z; v3 += r4.w;
                }
                if (GELU) {
                    v0 = 0.5f * v0 * (1.0f + erff(v0 * 0.70710678118654752f));
                    v1 = 0.5f * v1 * (1.0f + erff(v1 * 0.70710678118654752f));
                    v2 = 0.5f * v2 * (1.0f + erff(v2 * 0.70710678118654752f));
                    v3 = 0.5f * v3 * (1.0f + erff(v3 * 0.70710678118654752f));
                }
                if (OBF16) {
                    uint2 pk;
                    pk.x = pack2bf(v0, v1);
                    pk.y = pack2bf(v2, v3);
                    *(uint2*)((unsigned short*)Cv + (size_t)row * N + col0) = pk;
                } else {
                    float4 o4 = {v0, v1, v2, v3};
                    *(float4*)((float*)Cv + (size_t)row * N + col0) = o4;
                }
            }
        }
    } else {
        // original layout: thread holds col = ...+mlane, rows row0..row0+3
#pragma unroll
        for (int mi = 0; mi < MI; ++mi) {
#pragma unroll
            for (int ni = 0; ni < NI; ++ni) {
                const int col = n0 + wnrow + ni * 16 + mlane;
                const float bv = bias[col];
                const int row0 = m0 + wmrow + mi * 16 + quad * 4;
                if (VOUT && col >= 2048) {
                    // V output, transposed: vt[(b*16+h)*64+d][s], 4 consecutive s packed
                    const int vd = col - 2048;
                    const int bb = row0 >> 11, ss = row0 & 2047;
                    uint2 pk;
                    pk.x = pack2bf(acc[mi][ni][0] + bv, acc[mi][ni][1] + bv);
                    pk.y = pack2bf(acc[mi][ni][2] + bv, acc[mi][ni][3] + bv);
                    *(uint2*)(vtout + ((size_t)(bb * NH + (vd >> 6)) * DHEAD + (vd & 63)) * SEQ + ss) = pk;
                } else {
#pragma unroll
                    for (int rg = 0; rg < 4; ++rg) {
                        const int row = row0 + rg;
                        float v = acc[mi][ni][rg] + bv;
                        if (RES) v += res[(size_t)row * N + col];
                        if (GELU) v = 0.5f * v * (1.0f + erff(v * 0.70710678118654752f));
                        if (QSCALE && col < 1024) v *= 0.18033688011112042f;  // 0.125*log2(e)
                        if (OBF16)
                            ((unsigned short*)Cv)[(size_t)row * N + col] = f2bf(v);
                        else
                            ((float*)Cv)[(size_t)row * N + col] = v;
                    }
                }
            }
        }
    }
}

// ---------------- MFMA flash attention (causal), 64-key windows ----------------
// 1D grid of 1024 blocks x 256 threads (4 waves x 16 queries = 64 q/block).
// Block c (c<512) gets qt=31-(c>>5), block 512+c gets qt=(c>>5) -> pair work
// sums to 33 windows; whole grid co-resident (4 blocks/CU) for TLP.
// Per 64-key window: stage K(64x64) + V^T(64x64) in LDS (16B-chunk XOR
// swizzle), QK/PV MFMA with causal skip, exp2-domain online softmax
// (Q pre-scaled 0.125*log2e in QKV GEMM) with deferred-max rescale (THR=8),
// P^T via per-wave swizzled LDS round-trip, v_cvt_pk_bf16_f32 packs (T12).
__global__ __launch_bounds__(256, 4) void attn_kernel(const unsigned short* __restrict__ qkv,
                                                      const unsigned short* __restrict__ vt,
                                                      unsigned short* __restrict__ o) {
    const int g = blockIdx.x;
    const int qt = (g < 512) ? (31 - (g >> 5)) : ((g - 512) >> 5);
    const int hb = g & 31;
    const int h = hb & 15, b = hb >> 4;
    const int t = threadIdx.x;
    const int wave = t >> 6, lane = t & 63;
    const int mlane = lane & 15, quad = lane >> 4;
    const int msw = mlane & 7;  // read-side swizzle key (row & 7)
    const int wq0 = qt * 64 + wave * 16;
    const size_t bS = (size_t)b * SEQ;

    __shared__ unsigned short Ks[64][64];                    // [key][dim], swizzled
    __shared__ unsigned short Vs[64][64];                    // [dim][key], swizzled
    __shared__ __align__(16) unsigned short plds[4][16][64]; // [wave][q][key], swizzled

    short8v qf0, qf1;
    {
        const unsigned short* qrow = qkv + (bS + wq0 + mlane) * QKVD + h * DHEAD;
        qf0 = *(const short8v*)(qrow + quad * 8);
        qf1 = *(const short8v*)(qrow + 32 + quad * 8);
    }

    const unsigned short* kbase = qkv + bS * QKVD + 1024 + h * DHEAD;
    const unsigned short* vbase = vt + ((size_t)(b * NH + h)) * DHEAD * SEQ;

    // staging: 512 16B-chunks per 64x64 tile, 2 per thread (rows sr, 32+sr)
    const int sr = t >> 3, sc = t & 7;
    const int ssw = (sc ^ (sr & 7)) * 8;  // same key for row sr and 32+sr
    const unsigned short* kg0 = kbase + (size_t)sr * QKVD + sc * 8;
    const unsigned short* kg1 = kbase + (size_t)(32 + sr) * QKVD + sc * 8;
    const unsigned short* vg0 = vbase + (size_t)sr * SEQ + sc * 8;
    const unsigned short* vg1 = vbase + (size_t)(32 + sr) * SEQ + sc * 8;

    floatx4 ot[4];
#pragma unroll
    for (int mt = 0; mt < 4; ++mt) { floatx4 z = {0, 0, 0, 0}; ot[mt] = z; }
    float m_r = -INFINITY, l_r = 0.0f;

    const int kend = wq0 + 16;
    const int kmax = qt * 64 + 64;

    uint4 kr0 = *(const uint4*)kg0;
    uint4 kr1 = *(const uint4*)kg1;
    uint4 vr0 = *(const uint4*)vg0;
    uint4 vr1 = *(const uint4*)vg1;

    for (int k0 = 0; k0 < kmax; k0 += 64) {
        *(uint4*)&Ks[sr][ssw] = kr0;
        *(uint4*)&Ks[32 + sr][ssw] = kr1;
        *(uint4*)&Vs[sr][ssw] = vr0;
        *(uint4*)&Vs[32 + sr][ssw] = vr1;
        __syncthreads();
        if (k0 + 64 < kmax) {
            kr0 = *(const uint4*)(kg0 + (size_t)(k0 + 64) * QKVD);
            kr1 = *(const uint4*)(kg1 + (size_t)(k0 + 64) * QKVD);
            vr0 = *(const uint4*)(vg0 + (k0 + 64));
            vr1 = *(const uint4*)(vg1 + (k0 + 64));
        }
        if (k0 < kend) {
            // ---- S^T = K·Q^T over active 16-key tiles ----
            floatx4 st[4];
#pragma unroll
            for (int kt = 0; kt < 4; ++kt) {
                if (k0 + kt * 16 < kend) {
                    short8v kfa = *(const short8v*)&Ks[kt * 16 + mlane][(quad ^ msw) * 8];
                    short8v kfb = *(const short8v*)&Ks[kt * 16 + mlane][((quad + 4) ^ msw) * 8];
                    floatx4 z = {0, 0, 0, 0};
                    st[kt] = __builtin_amdgcn_mfma_f32_16x16x32_bf16(kfa, qf0, z, 0, 0, 0);
                    st[kt] = __builtin_amdgcn_mfma_f32_16x16x32_bf16(kfb, qf1, st[kt], 0, 0, 0);
                } else {
                    floatx4 mz = {-1e30f, -1e30f, -1e30f, -1e30f};
                    st[kt] = mz;
                }
            }
            // ---- causal mask (only the window straddling the diagonal) ----
            if (k0 + 64 >= kend) {
#pragma unroll
                for (int kt = 0; kt < 4; ++kt)
#pragma unroll
                    for (int rg = 0; rg < 4; ++rg)
                        if (k0 + kt * 16 + quad * 4 + rg > wq0 + mlane)
                            st[kt][rg] = -1e30f;
            }
            // ---- online softmax (exp2 domain), deferred-max rescale ----
            float tm = st[0][0];
#pragma unroll
            for (int kt = 0; kt < 4; ++kt)
#pragma unroll
                for (int rg = 0; rg < 4; ++rg) tm = fmaxf(tm, st[kt][rg]);
            tm = fmaxf(tm, __shfl_xor(tm, 16));
            tm = fmaxf(tm, __shfl_xor(tm, 32));
            if (!__all(tm <= m_r + 8.0f)) {
                const float newm = fmaxf(m_r, tm);
                const float alpha = exp2f(m_r - newm);
                l_r *= alpha;
#pragma unroll
                for (int mt = 0; mt < 4; ++mt)
#pragma unroll
                    for (int rg = 0; rg < 4; ++rg) ot[mt][rg] *= alpha;
                m_r = newm;
            }
            float p[4][4], psum = 0.0f;
#pragma unroll
            for (int kt = 0; kt < 4; ++kt)
#pragma unroll
                for (int rg = 0; rg < 4; ++rg) {
                    p[kt][rg] = exp2f(st[kt][rg] - m_r);
                    psum += p[kt][rg];
                }
            psum += __shfl_xor(psum, 16);
            psum += __shfl_xor(psum, 32);
            l_r += psum;
            // ---- P^T to LDS (swizzled, cvt_pk packs) ----
            char* prow = (char*)&plds[wave][mlane][0];
#pragma unroll
            for (int kt = 0; kt < 4; ++kt) {
                uint2 pk;
                pk.x = cvtpk2(p[kt][0], p[kt][1]);
                pk.y = cvtpk2(p[kt][2], p[kt][3]);
                *(uint2*)(prow + ((kt * 32 + quad * 8) ^ (msw << 4))) = pk;
            }
            // ---- O^T += V^T · P^T over active 32-key halves ----
#pragma unroll
            for (int kh = 0; kh < 2; ++kh) {
                if (k0 + kh * 32 < kend) {
                    short8v vf[4];
#pragma unroll
                    for (int mt = 0; mt < 4; ++mt)
                        vf[mt] = *(const short8v*)&Vs[mt * 16 + mlane][(((kh * 4 + quad) ^ msw)) * 8];
                    short8v pf = *(const short8v*)(prow + (((kh * 4 + quad) ^ msw) << 4));
#pragma unroll
                    for (int mt = 0; mt < 4; ++mt)
                        ot[mt] = __builtin_amdgcn_mfma_f32_16x16x32_bf16(vf[mt], pf, ot[mt], 0, 0, 0);
                }
            }
        }
        __syncthreads();
    }

    // epilogue
    const float inv = 1.0f / l_r;
    unsigned short* orow = o + (bS + wq0 + mlane) * BDIM + h * DHEAD;
#pragma unroll
    for (int mt = 0; mt < 4; ++mt) {
        uint2 pk;
        pk.x = cvtpk2(ot[mt][0] * inv, ot[mt][1] * inv);
        pk.y = cvtpk2(ot[mt][2] * inv, ot[mt][3] * inv);
        *(uint2*)(orow + mt * 16 + quad * 4) = pk;
    }
}

extern "C" void kernel_launch(void* const* d_in, const int* in_sizes, int n_in,
                              void* d_out, int out_size, void* d_ws, size_t ws_size,
                              hipStream_t stream) {
    const int M = 2 * SEQ;  // 4096

    const float* x = (const float*)d_in[0];
    const float* ln1_g = (const float*)d_in[1];
    const float* ln1_b = (const float*)d_in[2];
    const float* wq = (const float*)d_in[3];
    const float* bq = (const float*)d_in[4];
    const float* wk = (const float*)d_in[5];
    const float* bk = (const float*)d_in[6];
    const float* wv = (const float*)d_in[7];
    const float* bv = (const float*)d_in[8];
    const float* wo = (const float*)d_in[9];
    const float* bo = (const float*)d_in[10];
    const float* ln2_g = (const float*)d_in[11];
    const float* ln2_b = (const float*)d_in[12];
    const float* w1 = (const float*)d_in[13];
    const float* b1 = (const float*)d_in[14];
    const float* w2 = (const float*)d_in[15];
    const float* b2 = (const float*)d_in[16];

    char* wsb = (char*)d_ws;
    unsigned short* qkv = (unsigned short*)wsb;                    // [M][3072]
    unsigned short* ffn = (unsigned short*)wsb;                    // [M][4096] (later)
    unsigned short* vt = (unsigned short*)(wsb + (24u << 20));     // [32][64][2048]
    unsigned short* hbuf = (unsigned short*)(wsb + (32u << 20));   // h then o
    float* add1 = (float*)(wsb + (40u << 20));
    unsigned short* h2 = (unsigned short*)(wsb + (56u << 20));
    unsigned short* qkvT = (unsigned short*)(wsb + (64u << 20));
    unsigned short* woT = (unsigned short*)(wsb + (70u << 20));
    unsigned short* w1T = (unsigned short*)(wsb + (72u << 20));
    unsigned short* w2T = (unsigned short*)(wsb + (80u << 20));
    float* bqkv = (float*)(wsb + (88u << 20));

    // 0. weight convert+transpose (one launch), bias concat
    transpose_all<<<12288, 256, 0, stream>>>(wq, wk, wv, wo, w1, w2, qkvT, woT, w1T, w2T);
    concat_bias<<<12, 256, 0, stream>>>(bq, bk, bv, bqkv);

    // 1. h = LN1(x) -> bf16
    ln_kernel<<<M, 256, 0, stream>>>(x, ln1_g, ln1_b, hbuf);

    // 2. qkv = h @ [wq|wk|wv] + bias; Q pre-scaled 0.125*log2e; V transposed to vt
    mfma_gemm<128, 256, 64, 0, 0, 1, 1, 1, 0><<<dim3(QKVD / 256, M / 128), 256, 0, stream>>>(
        hbuf, qkvT, bqkv, nullptr, qkv, vt, M, QKVD, 1024);

    // 3. o = causal_attention(qkv, vt) -> hbuf; 1024 x 256 (4 blocks/CU TLP)
    attn_kernel<<<1024, 256, 0, stream>>>(qkv, vt, hbuf);

    // 4. add1 = o @ wo + bo + x (fp32); BK=128 (halved barrier count)
    mfma_gemm<128, 64, 128, 1, 0, 0, 0, 0, 1><<<dim3(1024 / 64, M / 128), 256, 0, stream>>>(
        hbuf, woT, bo, x, add1, nullptr, M, 1024, 1024);

    // 5. h2 = LN2(add1) -> bf16
    ln_kernel<<<M, 256, 0, stream>>>(add1, ln2_g, ln2_b, h2);

    // 6. ffn = gelu(h2 @ w1 + b1) -> bf16 — proven 2-phase BN=256
    mfma_gemm<128, 256, 64, 0, 1, 1, 0, 0, 1><<<dim3(FDIM / 256, M / 128), 256, 0, stream>>>(
        h2, w1T, b1, nullptr, ffn, nullptr, M, FDIM, 1024);

    // 7. out = ffn @ w2 + b2 + add1 -> fp32 d_out; BK=128
    mfma_gemm<128, 64, 128, 1, 0, 0, 0, 0, 1><<<dim3(1024 / 64, M / 128), 256, 0, stream>>>(
        ffn, w2T, b2, add1, (float*)d_out, nullptr, M, 1024, FDIM);
}